// Round 15
// baseline (157.502 us; speedup 1.0000x reference)
//
#include <hip/hip_runtime.h>

typedef unsigned short u16;
typedef unsigned int   u32;
typedef __bf16 bf16x8 __attribute__((ext_vector_type(8)));
typedef float  f32x4  __attribute__((ext_vector_type(4)));
typedef float  f32x16 __attribute__((ext_vector_type(16)));

#define DEV __device__ __forceinline__

DEV u16 f2bf(float f){ u32 u = __builtin_bit_cast(u32, f); u += 0x7fffu + ((u >> 16) & 1u); return (u16)(u >> 16); }
DEV float bf2f(u16 h){ u32 u = ((u32)h) << 16; return __builtin_bit_cast(float, u); }
DEV u32 pack2(float a, float b){ return (u32)f2bf(a) | ((u32)f2bf(b) << 16); }
DEV f32x4 mfma16(bf16x8 a, bf16x8 b, f32x4 c){ return __builtin_amdgcn_mfma_f32_16x16x32_bf16(a, b, c, 0, 0, 0); }
DEV f32x16 mfma32(bf16x8 a, bf16x8 b, f32x16 c){ return __builtin_amdgcn_mfma_f32_32x32x16_bf16(a, b, c, 0, 0, 0); }
DEV float gelu_exact(float x){ return 0.5f * x * (1.0f + erff(x * 0.70710678118654752f)); }
DEV u32 cvtpk(float a, float b){ u32 r; asm("v_cvt_pk_bf16_f32 %0, %1, %2" : "=v"(r) : "v"(a), "v"(b)); return r; }
DEV void gload16(const void* g, void* l){
  __builtin_amdgcn_global_load_lds((const __attribute__((address_space(1))) void*)g,
                                   (__attribute__((address_space(3))) void*)l, 16, 0, 0);
}

// ---------------------------------------------------------------------------
// combined prep: [0,5120) prep_wt | [5120,9216) conv_x | [9216,9222) small
__global__ __launch_bounds__(256) void prep_all(const float* x, const float* Wq, const float* Wk,
                                                const float* Wv, const float* Wo, const float* W1,
                                                const float* bq, const float* bk, const float* bv,
                                                const float* gq, const float* Bq, const float* gk, const float* Bk,
                                                const float* gv, const float* Bv,
                                                u16* WT, u16* xb, float* biasS, float* gS, float* BS){
  int bid = blockIdx.x, t = threadIdx.x;
  if (bid < 5120){
    int i = bid * 256 + t;
    int z = i >> 18, r = i & 262143;               // r = kk*512 + n
    const float* W = (z==0)?Wq : (z==1)?Wk : (z==2)?Wv : (z==3)?Wo : W1;
    int n = r & 511, kk = r >> 9;
    WT[(size_t)z * 262144 + (size_t)n * 512 + kk] = f2bf(W[r]);
  } else if (bid < 9216){
    size_t i = ((size_t)(bid - 5120) * 256 + t) * 8;
    float4 f0 = *(const float4*)(x + i), f1 = *(const float4*)(x + i + 4);
    uint4 o; o.x = pack2(f0.x, f0.y); o.y = pack2(f0.z, f0.w);
    o.z = pack2(f1.x, f1.y); o.w = pack2(f1.z, f1.w);
    *(uint4*)(xb + i) = o;
  } else {
    int i = (bid - 9216) * 256 + t;                // 0..1535
    int z = i >> 9, n = i & 511;
    biasS[i] = (z==0) ? bq[n] : (z==1) ? bk[n] : bv[n];
    gS[i]    = (z==0) ? gq[n] * 0.125f : (z==1) ? gk[n] : gv[n];
    BS[i]    = (z==0) ? Bq[n] * 0.125f : (z==1) ? Bk[n] : Bv[n];
  }
}

// ---------------------------------------------------------------------------
// 2-phase GEMM, 8 waves (512 thr, 2Mx4N wave grid, wave tile 64x32).
// A[M,512]bf16 @ WT[N,512]^T + bias -> C bf16 (ldc). BM=BN=128, BK=64.
// Same 64KB dbuf LDS / swizzle / coalesced epilogue as the 4-wave variant;
// 4 waves/SIMD at 2 blocks/CU doubles resident TLP to hide issue latency.
__global__ __launch_bounds__(512, 2) void gemm2(const u16* A, const u16* WT, const float* bias,
                                                u16* C, int ldc){
  int m0 = blockIdx.x * 128, n0 = blockIdx.y * 128;
  int t = threadIdx.x, l = t & 63, w = t >> 6;     // w in [0,8)
  int wm = (w >> 2) * 64, wn = (w & 3) * 32;
  int l15 = l & 15, lg = l >> 4;
  __shared__ uint4 smem[4096];                     // 64KB: A dbuf [0,2048) | B dbuf [2048,4096)
  f32x4 acc[4][2] = {};

  auto stage = [&](int buf, int kt){
#pragma unroll
    for (int p = 0; p < 2; ++p){
      int sbase = w * 128 + p * 64;                // wave-uniform LDS base; lane offset = l*16B
      int slot = sbase + l;
      int r = slot >> 3, bb = (slot & 7) ^ (r & 7);  // pre-swizzled global source
      gload16(A  + (size_t)(m0 + r) * 512 + kt * 64 + bb * 8, &smem[buf * 1024 + sbase]);
      gload16(WT + (size_t)(n0 + r) * 512 + kt * 64 + bb * 8, &smem[2048 + buf * 1024 + sbase]);
    }
  };

  stage(0, 0);
  __syncthreads();                                 // tile 0 ready
  for (int kk = 0; kk < 8; ++kk){
    int cur = kk & 1;
    if (kk < 7) stage(cur ^ 1, kk + 1);            // prefetch hides under compute
#pragma unroll
    for (int kf = 0; kf < 2; ++kf){
      bf16x8 a[4], b[2];
      int bb = kf * 4 + lg;
#pragma unroll
      for (int mf = 0; mf < 4; ++mf){
        int r = wm + mf * 16 + l15;
        a[mf] = __builtin_bit_cast(bf16x8, smem[cur * 1024 + r * 8 + (bb ^ (r & 7))]);
      }
#pragma unroll
      for (int nf = 0; nf < 2; ++nf){
        int r = wn + nf * 16 + l15;
        b[nf] = __builtin_bit_cast(bf16x8, smem[2048 + cur * 1024 + r * 8 + (bb ^ (r & 7))]);
      }
#pragma unroll
      for (int mf = 0; mf < 4; ++mf)
#pragma unroll
        for (int nf = 0; nf < 2; ++nf)
          acc[mf][nf] = mfma16(a[mf], b[nf], acc[mf][nf]);
    }
    __syncthreads();                               // readers done + prefetch landed
  }

  // ---- epilogue: +bias, bf16 -> LDS tile [128][152] u16, then coalesced stores.
  u16* tb = (u16*)smem;
#pragma unroll
  for (int nf = 0; nf < 2; ++nf){
    int cl = wn + nf * 16 + l15;
    float bv = bias[n0 + cl];
#pragma unroll
    for (int mf = 0; mf < 4; ++mf){
      int rl = wm + mf * 16 + lg * 4;
#pragma unroll
      for (int j = 0; j < 4; ++j)
        tb[(rl + j) * 152 + cl] = f2bf(acc[mf][nf][j] + bv);
    }
  }
  __syncthreads();
#pragma unroll
  for (int i = 0; i < 4; ++i){
    int row = i * 32 + (t >> 4), c8 = (t & 15) * 8;
    uint4 v = *(const uint4*)&tb[row * 152 + c8];
    *(uint4*)(C + (size_t)(m0 + row) * ldc + n0 + c8) = v;
  }
}

// ---------------------------------------------------------------------------
// fused LN over the 3 projection segments of P[16384][1536], in place.
__global__ __launch_bounds__(256) void ln3(u16* P, const float* gS, const float* BS){
  int w = threadIdx.x >> 6, l = threadIdx.x & 63;
  int z = blockIdx.x >> 12;
  size_t r = (size_t)(blockIdx.x & 4095) * 4 + w;
  u16* row = P + r * 1536 + z * 512;
  int n0 = l * 8, ng = z * 512 + n0;
  uint4 u = *(const uint4*)(row + n0);
  u32 ua[4] = {u.x, u.y, u.z, u.w};
  float v[8];
#pragma unroll
  for (int j = 0; j < 8; ++j) v[j] = bf2f((u16)(ua[j >> 1] >> ((j & 1) * 16)));
  float s = 0.f, sq = 0.f;
#pragma unroll
  for (int j = 0; j < 8; ++j){ s += v[j]; sq += v[j] * v[j]; }
  for (int d = 1; d < 64; d <<= 1){ s += __shfl_xor(s, d); sq += __shfl_xor(sq, d); }
  float mean = s * (1.0f / 512.0f);
  float rstd = rsqrtf(sq * (1.0f / 512.0f) - mean * mean + 1e-5f);
  u32 o[4];
#pragma unroll
  for (int jj = 0; jj < 4; ++jj){
    float y0 = (v[2*jj]   - mean) * rstd * gS[ng + 2*jj]   + BS[ng + 2*jj];
    float y1 = (v[2*jj+1] - mean) * rstd * gS[ng + 2*jj+1] + BS[ng + 2*jj+1];
    o[jj] = pack2(y0, y1);
  }
  uint4 ov; ov.x = o[0]; ov.y = o[1]; ov.z = o[2]; ov.w = o[3];
  *(uint4*)(row + n0) = ov;
}

// ---------------------------------------------------------------------------
// Flash attention, 32x32x16 MFMA, swapped QK^T (S^T = K Q^T), no-max softmax,
// in-register P->A-frag via cvt_pk + v_permlane32_swap. 4 waves x 32 q-rows.
__global__ __launch_bounds__(256, 3) void attn_k(const u16* qkv, u16* o){
  int bid = blockIdx.x;                            // 1024 blocks; XCD-bijective swizzle
  int swz = (bid & 7) * 128 + (bid >> 3);
  int qt = swz & 3, h = (swz >> 2) & 7, b = swz >> 5;
  int t = threadIdx.x, l = t & 63, w = t >> 6, l31 = l & 31, hl = l >> 5;
  __shared__ uint4 Ks[2][512];                     // [64 s][8 blk] swizzled (blk ^ (s&7))
  __shared__ uint4 Vt[2][512];                     // V^T [64 d][8 blk] swizzled

  int qrow0 = b * 512 + qt * 128 + w * 32;
  const u16* qp = qkv + (size_t)qrow0 * 1536 + h * 64;
  const u16* kp = qkv + (size_t)(b * 512) * 1536 + 512  + h * 64;
  const u16* vp = qkv + (size_t)(b * 512) * 1536 + 1024 + h * 64;

  bf16x8 bq[4];
#pragma unroll
  for (int tp = 0; tp < 4; ++tp)
    bq[tp] = *(const bf16x8*)(qp + (size_t)l31 * 1536 + tp * 16 + hl * 8);

  int dg = t & 15, sgrp = t >> 4;
  int bs = sgrp >> 1, hq = sgrp & 1;
  const u32 sel0 = 0x05040100u, sel1 = 0x07060302u;
  uint2 vld0, vld1, vld2, vld3;

#pragma unroll
  for (int p = 0; p < 2; ++p){
    int sbase = w * 128 + p * 64;
    int slot = sbase + l;
    int r = slot >> 3, bb = (slot & 7) ^ (r & 7);
    gload16(kp + (size_t)r * 1536 + bb * 8, &Ks[0][sbase]);
  }
  vld0 = *(const uint2*)(vp + (size_t)(sgrp * 4 + 0) * 1536 + dg * 4);
  vld1 = *(const uint2*)(vp + (size_t)(sgrp * 4 + 1) * 1536 + dg * 4);
  vld2 = *(const uint2*)(vp + (size_t)(sgrp * 4 + 2) * 1536 + dg * 4);
  vld3 = *(const uint2*)(vp + (size_t)(sgrp * 4 + 3) * 1536 + dg * 4);
  {
    u16* base = (u16*)&Vt[0][0];
#pragma unroll
    for (int j = 0; j < 4; ++j){
      u32 lo = (j < 2) ? __builtin_amdgcn_perm(vld1.x, vld0.x, (j & 1) ? sel1 : sel0)
                       : __builtin_amdgcn_perm(vld1.y, vld0.y, (j & 1) ? sel1 : sel0);
      u32 hi = (j < 2) ? __builtin_amdgcn_perm(vld3.x, vld2.x, (j & 1) ? sel1 : sel0)
                       : __builtin_amdgcn_perm(vld3.y, vld2.y, (j & 1) ? sel1 : sel0);
      int d = dg * 4 + j;
      uint2 cj; cj.x = lo; cj.y = hi;
      *(uint2*)(base + d * 64 + (bs ^ (d & 7)) * 8 + hq * 4) = cj;
    }
  }
  __syncthreads();

  f32x16 Od0 = {}, Od1 = {};
  float lsum = 0.f;

  for (int tile = 0; tile < 8; ++tile){
    int cur = tile & 1;
    if (tile < 7){
      int s0n = (tile + 1) * 64;
#pragma unroll
      for (int p = 0; p < 2; ++p){
        int sbase = w * 128 + p * 64;
        int slot = sbase + l;
        int r = slot >> 3, bb = (slot & 7) ^ (r & 7);
        gload16(kp + (size_t)(s0n + r) * 1536 + bb * 8, &Ks[cur ^ 1][sbase]);
      }
      vld0 = *(const uint2*)(vp + (size_t)(s0n + sgrp * 4 + 0) * 1536 + dg * 4);
      vld1 = *(const uint2*)(vp + (size_t)(s0n + sgrp * 4 + 1) * 1536 + dg * 4);
      vld2 = *(const uint2*)(vp + (size_t)(s0n + sgrp * 4 + 2) * 1536 + dg * 4);
      vld3 = *(const uint2*)(vp + (size_t)(s0n + sgrp * 4 + 3) * 1536 + dg * 4);
    }

    f32x16 S0 = {}, S1 = {};
#pragma unroll
    for (int tp = 0; tp < 4; ++tp){
      int bb = 2 * tp + hl;
      int r0 = l31, r1 = 32 + l31;
      bf16x8 k0 = __builtin_bit_cast(bf16x8, Ks[cur][r0 * 8 + (bb ^ (r0 & 7))]);
      bf16x8 k1 = __builtin_bit_cast(bf16x8, Ks[cur][r1 * 8 + (bb ^ (r1 & 7))]);
      S0 = mfma32(k0, bq[tp], S0);
      S1 = mfma32(k1, bq[tp], S1);
    }

    u32 W0[8], W1[8];
#pragma unroll
    for (int m = 0; m < 8; ++m){
      float e0 = __expf(S0[2 * m]), e1 = __expf(S0[2 * m + 1]);
      float f0 = __expf(S1[2 * m]), f1 = __expf(S1[2 * m + 1]);
      lsum += (e0 + e1) + (f0 + f1);
      W0[m] = cvtpk(e0, e1);
      W1[m] = cvtpk(f0, f1);
    }

    bf16x8 pa[4];
#pragma unroll
    for (int tt = 0; tt < 4; ++tt){
      int m0 = (tt & 1) * 4;
      u32 a0 = (tt < 2) ? W0[m0]     : W1[m0];
      u32 c0 = (tt < 2) ? W0[m0 + 2] : W1[m0 + 2];
      u32 a1 = (tt < 2) ? W0[m0 + 1] : W1[m0 + 1];
      u32 c1 = (tt < 2) ? W0[m0 + 3] : W1[m0 + 3];
      asm volatile("v_permlane32_swap_b32 %0, %1" : "+v"(a0), "+v"(c0));
      asm volatile("v_permlane32_swap_b32 %0, %1" : "+v"(a1), "+v"(c1));
      uint4 pf; pf.x = a0; pf.y = a1; pf.z = c0; pf.w = c1;
      pa[tt] = __builtin_bit_cast(bf16x8, pf);
    }

#pragma unroll
    for (int tt = 0; tt < 4; ++tt){
      int bb = 2 * tt + hl;
      int r0 = l31, r1 = 32 + l31;
      bf16x8 v0 = __builtin_bit_cast(bf16x8, Vt[cur][r0 * 8 + (bb ^ (r0 & 7))]);
      bf16x8 v1 = __builtin_bit_cast(bf16x8, Vt[cur][r1 * 8 + (bb ^ (r1 & 7))]);
      Od0 = mfma32(v0, pa[tt], Od0);
      Od1 = mfma32(v1, pa[tt], Od1);
    }

    if (tile < 7){
      u16* base = (u16*)&Vt[cur ^ 1][0];
#pragma unroll
      for (int j = 0; j < 4; ++j){
        u32 lo = (j < 2) ? __builtin_amdgcn_perm(vld1.x, vld0.x, (j & 1) ? sel1 : sel0)
                         : __builtin_amdgcn_perm(vld1.y, vld0.y, (j & 1) ? sel1 : sel0);
        u32 hi = (j < 2) ? __builtin_amdgcn_perm(vld3.x, vld2.x, (j & 1) ? sel1 : sel0)
                         : __builtin_amdgcn_perm(vld3.y, vld2.y, (j & 1) ? sel1 : sel0);
        int d = dg * 4 + j;
        uint2 cj; cj.x = lo; cj.y = hi;
        *(uint2*)(base + d * 64 + (bs ^ (d & 7)) * 8 + hq * 4) = cj;
      }
    }
    __syncthreads();
  }

  float inv = 1.0f / (lsum + __shfl_xor(lsum, 32));
  u16* op = o + (size_t)qrow0 * 512 + h * 64;
#pragma unroll
  for (int db = 0; db < 2; ++db){
#pragma unroll
    for (int c = 0; c < 4; ++c){
      float p0 = ((db ? Od1 : Od0)[4 * c + 0]) * inv;
      float p1 = ((db ? Od1 : Od0)[4 * c + 1]) * inv;
      float p2 = ((db ? Od1 : Od0)[4 * c + 2]) * inv;
      float p3 = ((db ? Od1 : Od0)[4 * c + 3]) * inv;
      uint2 ov; ov.x = cvtpk(p0, p1); ov.y = cvtpk(p2, p3);
      *(uint2*)(op + (size_t)l31 * 512 + db * 32 + c * 8 + hl * 4) = ov;
    }
  }
}

// ---------------------------------------------------------------------------
// GELU(Po) + x residual + LayerNorm -> out f32 AND x2b bf16
__global__ __launch_bounds__(256) void ln_o(const u16* P, const float* x, const float* g, const float* B,
                                            float* out, u16* x2b){
  int w = threadIdx.x >> 6, l = threadIdx.x & 63;
  size_t r = (size_t)blockIdx.x * 4 + w;
  int n0 = l * 8;
  uint4 u = *(const uint4*)(P + r * 512 + n0);
  u32 ua[4] = {u.x, u.y, u.z, u.w};
  float4 x0 = *(const float4*)(x + r * 512 + n0);
  float4 x1 = *(const float4*)(x + r * 512 + n0 + 4);
  float xv[8] = {x0.x, x0.y, x0.z, x0.w, x1.x, x1.y, x1.z, x1.w};
  float v[8];
#pragma unroll
  for (int j = 0; j < 8; ++j){
    float pv = bf2f((u16)(ua[j >> 1] >> ((j & 1) * 16)));
    v[j] = gelu_exact(pv) + xv[j];
  }
  float s = 0.f, sq = 0.f;
#pragma unroll
  for (int j = 0; j < 8; ++j){ s += v[j]; sq += v[j] * v[j]; }
  for (int d = 1; d < 64; d <<= 1){ s += __shfl_xor(s, d); sq += __shfl_xor(sq, d); }
  float mean = s * (1.0f / 512.0f);
  float rstd = rsqrtf(sq * (1.0f / 512.0f) - mean * mean + 1e-5f);
  float y[8];
#pragma unroll
  for (int j = 0; j < 8; ++j) y[j] = (v[j] - mean) * rstd * g[n0 + j] + B[n0 + j];
  float4 o0, o1;
  o0.x = y[0]; o0.y = y[1]; o0.z = y[2]; o0.w = y[3];
  o1.x = y[4]; o1.y = y[5]; o1.z = y[6]; o1.w = y[7];
  *(float4*)(out + r * 512 + n0) = o0;
  *(float4*)(out + r * 512 + n0 + 4) = o1;
  uint4 ob; ob.x = pack2(y[0], y[1]); ob.y = pack2(y[2], y[3]);
  ob.z = pack2(y[4], y[5]); ob.w = pack2(y[6], y[7]);
  *(uint4*)(x2b + r * 512 + n0) = ob;
}

// ---------------------------------------------------------------------------
// w[row] = sum_n gelu(P1[row,n]) * W2[n] + b2  (full occupancy)
__global__ __launch_bounds__(256) void red_m(const u16* P, const float* W2, const float* b2, float* wv){
  int w = threadIdx.x >> 6, l = threadIdx.x & 63;
  size_t r = (size_t)blockIdx.x * 4 + w;
  int n0 = l * 8;
  uint4 u = *(const uint4*)(P + r * 512 + n0);
  u32 ua[4] = {u.x, u.y, u.z, u.w};
  float acc = 0.f;
#pragma unroll
  for (int j = 0; j < 8; ++j){
    float pv = bf2f((u16)(ua[j >> 1] >> ((j & 1) * 16)));
    acc += gelu_exact(pv) * W2[n0 + j];
  }
  for (int d = 1; d < 64; d <<= 1) acc += __shfl_xor(acc, d);
  if (l == 0) wv[r] = acc + b2[0];
}

__global__ __launch_bounds__(64) void fi_k(const float* wv, float* out){
  int b = blockIdx.x, l = threadIdx.x;
  float x[8]; float mx = -3.0e38f;
#pragma unroll
  for (int i = 0; i < 8; ++i){ x[i] = wv[b * 512 + i * 64 + l]; mx = fmaxf(mx, x[i]); }
  for (int d = 1; d < 64; d <<= 1) mx = fmaxf(mx, __shfl_xor(mx, d));
  float s = 0.f;
#pragma unroll
  for (int i = 0; i < 8; ++i){ x[i] = __expf(x[i] - mx); s += x[i]; }
  for (int d = 1; d < 64; d <<= 1) s += __shfl_xor(s, d);
  float inv = 1.0f / s;
#pragma unroll
  for (int i = 0; i < 8; ++i) out[b * 512 + i * 64 + l] = x[i] * inv;
}

// ---------------------------------------------------------------------------
extern "C" void kernel_launch(void* const* d_in, const int* in_sizes, int n_in,
                              void* d_out, int out_size, void* d_ws, size_t ws_size,
                              hipStream_t stream){
  const float* x    = (const float*)d_in[0];
  const float* Wq   = (const float*)d_in[1];
  const float* bq   = (const float*)d_in[2];
  const float* Wk   = (const float*)d_in[3];
  const float* bk   = (const float*)d_in[4];
  const float* Wv   = (const float*)d_in[5];
  const float* bv   = (const float*)d_in[6];
  const float* gq   = (const float*)d_in[7];
  const float* Bq   = (const float*)d_in[8];
  const float* gk   = (const float*)d_in[9];
  const float* Bk   = (const float*)d_in[10];
  const float* gv   = (const float*)d_in[11];
  const float* Bv   = (const float*)d_in[12];
  const float* Wo   = (const float*)d_in[13];
  const float* bo   = (const float*)d_in[14];
  const float* g_ln = (const float*)d_in[15];
  const float* b_ln = (const float*)d_in[16];
  const float* W1   = (const float*)d_in[17];
  const float* b1   = (const float*)d_in[18];
  const float* W2   = (const float*)d_in[19];
  const float* b2   = (const float*)d_in[20];
  float* out = (float*)d_out;

  char* ws = (char*)d_ws;
  u16*   WT    = (u16*)(ws);                         // 2,621,440 B
  float* biasS = (float*)(ws + 2621440);             // 6144
  float* gS    = (float*)(ws + 2627584);             // 6144
  float* BS    = (float*)(ws + 2633728);             // 6144
  u16*   xb    = (u16*)(ws + 2639872);               // 16,777,216 (reused as `at` after qkv gemm)
  u16*   at    = xb;
  u16*   P     = (u16*)(ws + 19417088);              // 50,331,648 ([16384][1536])
  u16*   Po    = P;                                  // [16384][512], P dead after attn
  u16*   x2b   = (u16*)((char*)P + 16777216);
  u16*   P1    = (u16*)((char*)P + 33554432);
  float* wvec  = (float*)(ws + 69748736);            // 65,536

  prep_all<<<9222, 256, 0, stream>>>(x, Wq, Wk, Wv, Wo, W1, bq, bk, bv,
                                     gq, Bq, gk, Bk, gv, Bv, WT, xb, biasS, gS, BS);

  gemm2<<<dim3(128, 12), 512, 0, stream>>>(xb, WT, biasS, P, 1536);       // fused QKV
  ln3<<<12288, 256, 0, stream>>>(P, gS, BS);                              // in-place, q pre-scaled

  attn_k<<<1024, 256, 0, stream>>>(P, at);

  gemm2<<<dim3(128, 4), 512, 0, stream>>>(at, WT + 3 * 262144, bo, Po, 512);
  ln_o<<<4096, 256, 0, stream>>>(Po, x, g_ln, b_ln, out, x2b);

  gemm2<<<dim3(128, 4), 512, 0, stream>>>(x2b, WT + 4 * 262144, b1, P1, 512);
  red_m<<<4096, 256, 0, stream>>>(P1, W2, b2, wvec);
  fi_k<<<32, 64, 0, stream>>>(wvec, out + 8388608);
}

// Round 16
// 155.212 us; speedup vs baseline: 1.0148x; 1.0148x over previous
//
#include <hip/hip_runtime.h>

typedef unsigned short u16;
typedef unsigned int   u32;
typedef __bf16 bf16x8 __attribute__((ext_vector_type(8)));
typedef float  f32x4  __attribute__((ext_vector_type(4)));
typedef float  f32x16 __attribute__((ext_vector_type(16)));

#define DEV __device__ __forceinline__

DEV u16 f2bf(float f){ u32 u = __builtin_bit_cast(u32, f); u += 0x7fffu + ((u >> 16) & 1u); return (u16)(u >> 16); }
DEV float bf2f(u16 h){ u32 u = ((u32)h) << 16; return __builtin_bit_cast(float, u); }
DEV u32 pack2(float a, float b){ return (u32)f2bf(a) | ((u32)f2bf(b) << 16); }
DEV f32x4 mfma16(bf16x8 a, bf16x8 b, f32x4 c){ return __builtin_amdgcn_mfma_f32_16x16x32_bf16(a, b, c, 0, 0, 0); }
DEV f32x16 mfma32(bf16x8 a, bf16x8 b, f32x16 c){ return __builtin_amdgcn_mfma_f32_32x32x16_bf16(a, b, c, 0, 0, 0); }
DEV float gelu_exact(float x){ return 0.5f * x * (1.0f + erff(x * 0.70710678118654752f)); }
DEV u32 cvtpk(float a, float b){ u32 r; asm("v_cvt_pk_bf16_f32 %0, %1, %2" : "=v"(r) : "v"(a), "v"(b)); return r; }
DEV void gload16(const void* g, void* l){
  __builtin_amdgcn_global_load_lds((const __attribute__((address_space(1))) void*)g,
                                   (__attribute__((address_space(3))) void*)l, 16, 0, 0);
}

// ---------------------------------------------------------------------------
// combined prep: [0,5120) prep_wt | [5120,9216) conv_x | [9216,9222) small
__global__ __launch_bounds__(256) void prep_all(const float* x, const float* Wq, const float* Wk,
                                                const float* Wv, const float* Wo, const float* W1,
                                                const float* bq, const float* bk, const float* bv,
                                                const float* gq, const float* Bq, const float* gk, const float* Bk,
                                                const float* gv, const float* Bv,
                                                u16* WT, u16* xb, float* biasS, float* gS, float* BS){
  int bid = blockIdx.x, t = threadIdx.x;
  if (bid < 5120){
    int i = bid * 256 + t;
    int z = i >> 18, r = i & 262143;               // r = kk*512 + n
    const float* W = (z==0)?Wq : (z==1)?Wk : (z==2)?Wv : (z==3)?Wo : W1;
    int n = r & 511, kk = r >> 9;
    WT[(size_t)z * 262144 + (size_t)n * 512 + kk] = f2bf(W[r]);
  } else if (bid < 9216){
    size_t i = ((size_t)(bid - 5120) * 256 + t) * 8;
    float4 f0 = *(const float4*)(x + i), f1 = *(const float4*)(x + i + 4);
    uint4 o; o.x = pack2(f0.x, f0.y); o.y = pack2(f0.z, f0.w);
    o.z = pack2(f1.x, f1.y); o.w = pack2(f1.z, f1.w);
    *(uint4*)(xb + i) = o;
  } else {
    int i = (bid - 9216) * 256 + t;                // 0..1535
    int z = i >> 9, n = i & 511;
    biasS[i] = (z==0) ? bq[n] : (z==1) ? bk[n] : bv[n];
    gS[i]    = (z==0) ? gq[n] * 0.125f : (z==1) ? gk[n] : gv[n];
    BS[i]    = (z==0) ? Bq[n] * 0.125f : (z==1) ? Bk[n] : Bv[n];
  }
}

// ---------------------------------------------------------------------------
// 2-phase GEMM (R5/R8 loop) + LDS-transposed coalesced epilogue.
// A[M,512]bf16 @ WT[N,512]^T + bias -> C bf16 (ldc). BM=BN=128, BK=64.
// Epilogue: acc -> bf16 tile in LDS (pad stride 152 u16) -> 16B/lane stores.
__global__ __launch_bounds__(256, 2) void gemm2(const u16* A, const u16* WT, const float* bias,
                                                u16* C, int ldc){
  int m0 = blockIdx.x * 128, n0 = blockIdx.y * 128;
  int t = threadIdx.x, l = t & 63, w = t >> 6;
  int wm = (w >> 1) * 64, wn = (w & 1) * 64;
  int l15 = l & 15, lg = l >> 4;
  __shared__ uint4 smem[4096];                     // 64KB: A dbuf [0,2048) | B dbuf [2048,4096)
  f32x4 acc[4][4] = {};

  auto stage = [&](int buf, int kt){
#pragma unroll
    for (int p = 0; p < 4; ++p){
      int sbase = w * 256 + p * 64;                // wave-uniform LDS base; lane offset = l*16B
      int slot = sbase + l;
      int r = slot >> 3, bb = (slot & 7) ^ (r & 7);  // pre-swizzled global source
      gload16(A  + (size_t)(m0 + r) * 512 + kt * 64 + bb * 8, &smem[buf * 1024 + sbase]);
      gload16(WT + (size_t)(n0 + r) * 512 + kt * 64 + bb * 8, &smem[2048 + buf * 1024 + sbase]);
    }
  };

  stage(0, 0);
  __syncthreads();                                 // tile 0 ready
  for (int kk = 0; kk < 8; ++kk){
    int cur = kk & 1;
    if (kk < 7) stage(cur ^ 1, kk + 1);            // prefetch hides under compute
#pragma unroll
    for (int kf = 0; kf < 2; ++kf){
      bf16x8 a[4], b[4];
      int bb = kf * 4 + lg;
#pragma unroll
      for (int mf = 0; mf < 4; ++mf){
        int r = wm + mf * 16 + l15;
        a[mf] = __builtin_bit_cast(bf16x8, smem[cur * 1024 + r * 8 + (bb ^ (r & 7))]);
      }
#pragma unroll
      for (int nf = 0; nf < 4; ++nf){
        int r = wn + nf * 16 + l15;
        b[nf] = __builtin_bit_cast(bf16x8, smem[2048 + cur * 1024 + r * 8 + (bb ^ (r & 7))]);
      }
#pragma unroll
      for (int mf = 0; mf < 4; ++mf)
#pragma unroll
        for (int nf = 0; nf < 4; ++nf)
          acc[mf][nf] = mfma16(a[mf], b[nf], acc[mf][nf]);
    }
    __syncthreads();                               // readers done + prefetch landed
  }

  // ---- epilogue: +bias, bf16 -> LDS tile [128][152] u16 (pad, 304B stride), then coalesced stores.
  u16* tb = (u16*)smem;
#pragma unroll
  for (int nf = 0; nf < 4; ++nf){
    int cl = wn + nf * 16 + l15;
    float bv = bias[n0 + cl];
#pragma unroll
    for (int mf = 0; mf < 4; ++mf){
      int rl = wm + mf * 16 + lg * 4;
#pragma unroll
      for (int j = 0; j < 4; ++j)
        tb[(rl + j) * 152 + cl] = f2bf(acc[mf][nf][j] + bv);
    }
  }
  __syncthreads();
#pragma unroll
  for (int i = 0; i < 8; ++i){
    int row = i * 16 + (t >> 4), c8 = (t & 15) * 8;
    uint4 v = *(const uint4*)&tb[row * 152 + c8];
    *(uint4*)(C + (size_t)(m0 + row) * ldc + n0 + c8) = v;
  }
}

// ---------------------------------------------------------------------------
// fused LN over the 3 projection segments of P[16384][1536], in place.
__global__ __launch_bounds__(256) void ln3(u16* P, const float* gS, const float* BS){
  int w = threadIdx.x >> 6, l = threadIdx.x & 63;
  int z = blockIdx.x >> 12;
  size_t r = (size_t)(blockIdx.x & 4095) * 4 + w;
  u16* row = P + r * 1536 + z * 512;
  int n0 = l * 8, ng = z * 512 + n0;
  uint4 u = *(const uint4*)(row + n0);
  u32 ua[4] = {u.x, u.y, u.z, u.w};
  float v[8];
#pragma unroll
  for (int j = 0; j < 8; ++j) v[j] = bf2f((u16)(ua[j >> 1] >> ((j & 1) * 16)));
  float s = 0.f, sq = 0.f;
#pragma unroll
  for (int j = 0; j < 8; ++j){ s += v[j]; sq += v[j] * v[j]; }
  for (int d = 1; d < 64; d <<= 1){ s += __shfl_xor(s, d); sq += __shfl_xor(sq, d); }
  float mean = s * (1.0f / 512.0f);
  float rstd = rsqrtf(sq * (1.0f / 512.0f) - mean * mean + 1e-5f);
  u32 o[4];
#pragma unroll
  for (int jj = 0; jj < 4; ++jj){
    float y0 = (v[2*jj]   - mean) * rstd * gS[ng + 2*jj]   + BS[ng + 2*jj];
    float y1 = (v[2*jj+1] - mean) * rstd * gS[ng + 2*jj+1] + BS[ng + 2*jj+1];
    o[jj] = pack2(y0, y1);
  }
  uint4 ov; ov.x = o[0]; ov.y = o[1]; ov.z = o[2]; ov.w = o[3];
  *(uint4*)(row + n0) = ov;
}

// ---------------------------------------------------------------------------
// Flash attention, 32x32x16 MFMA, swapped QK^T (S^T = K Q^T), no-max softmax,
// in-register P->A-frag via cvt_pk + v_permlane32_swap. 4 waves x 32 q-rows.
__global__ __launch_bounds__(256, 3) void attn_k(const u16* qkv, u16* o){
  int bid = blockIdx.x;                            // 1024 blocks; XCD-bijective swizzle
  int swz = (bid & 7) * 128 + (bid >> 3);
  int qt = swz & 3, h = (swz >> 2) & 7, b = swz >> 5;
  int t = threadIdx.x, l = t & 63, w = t >> 6, l31 = l & 31, hl = l >> 5;
  __shared__ uint4 Ks[2][512];                     // [64 s][8 blk] swizzled (blk ^ (s&7))
  __shared__ uint4 Vt[2][512];                     // V^T [64 d][8 blk] swizzled

  int qrow0 = b * 512 + qt * 128 + w * 32;
  const u16* qp = qkv + (size_t)qrow0 * 1536 + h * 64;
  const u16* kp = qkv + (size_t)(b * 512) * 1536 + 512  + h * 64;
  const u16* vp = qkv + (size_t)(b * 512) * 1536 + 1024 + h * 64;

  bf16x8 bq[4];
#pragma unroll
  for (int tp = 0; tp < 4; ++tp)
    bq[tp] = *(const bf16x8*)(qp + (size_t)l31 * 1536 + tp * 16 + hl * 8);

  int dg = t & 15, sgrp = t >> 4;
  int bs = sgrp >> 1, hq = sgrp & 1;
  const u32 sel0 = 0x05040100u, sel1 = 0x07060302u;
  uint2 vld0, vld1, vld2, vld3;

#pragma unroll
  for (int p = 0; p < 2; ++p){
    int sbase = w * 128 + p * 64;
    int slot = sbase + l;
    int r = slot >> 3, bb = (slot & 7) ^ (r & 7);
    gload16(kp + (size_t)r * 1536 + bb * 8, &Ks[0][sbase]);
  }
  vld0 = *(const uint2*)(vp + (size_t)(sgrp * 4 + 0) * 1536 + dg * 4);
  vld1 = *(const uint2*)(vp + (size_t)(sgrp * 4 + 1) * 1536 + dg * 4);
  vld2 = *(const uint2*)(vp + (size_t)(sgrp * 4 + 2) * 1536 + dg * 4);
  vld3 = *(const uint2*)(vp + (size_t)(sgrp * 4 + 3) * 1536 + dg * 4);
  {
    u16* base = (u16*)&Vt[0][0];
#pragma unroll
    for (int j = 0; j < 4; ++j){
      u32 lo = (j < 2) ? __builtin_amdgcn_perm(vld1.x, vld0.x, (j & 1) ? sel1 : sel0)
                       : __builtin_amdgcn_perm(vld1.y, vld0.y, (j & 1) ? sel1 : sel0);
      u32 hi = (j < 2) ? __builtin_amdgcn_perm(vld3.x, vld2.x, (j & 1) ? sel1 : sel0)
                       : __builtin_amdgcn_perm(vld3.y, vld2.y, (j & 1) ? sel1 : sel0);
      int d = dg * 4 + j;
      uint2 cj; cj.x = lo; cj.y = hi;
      *(uint2*)(base + d * 64 + (bs ^ (d & 7)) * 8 + hq * 4) = cj;
    }
  }
  __syncthreads();

  f32x16 Od0 = {}, Od1 = {};
  float lsum = 0.f;

  for (int tile = 0; tile < 8; ++tile){
    int cur = tile & 1;
    if (tile < 7){
      int s0n = (tile + 1) * 64;
#pragma unroll
      for (int p = 0; p < 2; ++p){
        int sbase = w * 128 + p * 64;
        int slot = sbase + l;
        int r = slot >> 3, bb = (slot & 7) ^ (r & 7);
        gload16(kp + (size_t)(s0n + r) * 1536 + bb * 8, &Ks[cur ^ 1][sbase]);
      }
      vld0 = *(const uint2*)(vp + (size_t)(s0n + sgrp * 4 + 0) * 1536 + dg * 4);
      vld1 = *(const uint2*)(vp + (size_t)(s0n + sgrp * 4 + 1) * 1536 + dg * 4);
      vld2 = *(const uint2*)(vp + (size_t)(s0n + sgrp * 4 + 2) * 1536 + dg * 4);
      vld3 = *(const uint2*)(vp + (size_t)(s0n + sgrp * 4 + 3) * 1536 + dg * 4);
    }

    f32x16 S0 = {}, S1 = {};
#pragma unroll
    for (int tp = 0; tp < 4; ++tp){
      int bb = 2 * tp + hl;
      int r0 = l31, r1 = 32 + l31;
      bf16x8 k0 = __builtin_bit_cast(bf16x8, Ks[cur][r0 * 8 + (bb ^ (r0 & 7))]);
      bf16x8 k1 = __builtin_bit_cast(bf16x8, Ks[cur][r1 * 8 + (bb ^ (r1 & 7))]);
      S0 = mfma32(k0, bq[tp], S0);
      S1 = mfma32(k1, bq[tp], S1);
    }

    u32 W0[8], W1[8];
#pragma unroll
    for (int m = 0; m < 8; ++m){
      float e0 = __expf(S0[2 * m]), e1 = __expf(S0[2 * m + 1]);
      float f0 = __expf(S1[2 * m]), f1 = __expf(S1[2 * m + 1]);
      lsum += (e0 + e1) + (f0 + f1);
      W0[m] = cvtpk(e0, e1);
      W1[m] = cvtpk(f0, f1);
    }

    bf16x8 pa[4];
#pragma unroll
    for (int tt = 0; tt < 4; ++tt){
      int m0 = (tt & 1) * 4;
      u32 a0 = (tt < 2) ? W0[m0]     : W1[m0];
      u32 c0 = (tt < 2) ? W0[m0 + 2] : W1[m0 + 2];
      u32 a1 = (tt < 2) ? W0[m0 + 1] : W1[m0 + 1];
      u32 c1 = (tt < 2) ? W0[m0 + 3] : W1[m0 + 3];
      asm volatile("v_permlane32_swap_b32 %0, %1" : "+v"(a0), "+v"(c0));
      asm volatile("v_permlane32_swap_b32 %0, %1" : "+v"(a1), "+v"(c1));
      uint4 pf; pf.x = a0; pf.y = a1; pf.z = c0; pf.w = c1;
      pa[tt] = __builtin_bit_cast(bf16x8, pf);
    }

#pragma unroll
    for (int tt = 0; tt < 4; ++tt){
      int bb = 2 * tt + hl;
      int r0 = l31, r1 = 32 + l31;
      bf16x8 v0 = __builtin_bit_cast(bf16x8, Vt[cur][r0 * 8 + (bb ^ (r0 & 7))]);
      bf16x8 v1 = __builtin_bit_cast(bf16x8, Vt[cur][r1 * 8 + (bb ^ (r1 & 7))]);
      Od0 = mfma32(v0, pa[tt], Od0);
      Od1 = mfma32(v1, pa[tt], Od1);
    }

    if (tile < 7){
      u16* base = (u16*)&Vt[cur ^ 1][0];
#pragma unroll
      for (int j = 0; j < 4; ++j){
        u32 lo = (j < 2) ? __builtin_amdgcn_perm(vld1.x, vld0.x, (j & 1) ? sel1 : sel0)
                         : __builtin_amdgcn_perm(vld1.y, vld0.y, (j & 1) ? sel1 : sel0);
        u32 hi = (j < 2) ? __builtin_amdgcn_perm(vld3.x, vld2.x, (j & 1) ? sel1 : sel0)
                         : __builtin_amdgcn_perm(vld3.y, vld2.y, (j & 1) ? sel1 : sel0);
        int d = dg * 4 + j;
        uint2 cj; cj.x = lo; cj.y = hi;
        *(uint2*)(base + d * 64 + (bs ^ (d & 7)) * 8 + hq * 4) = cj;
      }
    }
    __syncthreads();
  }

  float inv = 1.0f / (lsum + __shfl_xor(lsum, 32));
  u16* op = o + (size_t)qrow0 * 512 + h * 64;
#pragma unroll
  for (int db = 0; db < 2; ++db){
#pragma unroll
    for (int c = 0; c < 4; ++c){
      float p0 = ((db ? Od1 : Od0)[4 * c + 0]) * inv;
      float p1 = ((db ? Od1 : Od0)[4 * c + 1]) * inv;
      float p2 = ((db ? Od1 : Od0)[4 * c + 2]) * inv;
      float p3 = ((db ? Od1 : Od0)[4 * c + 3]) * inv;
      uint2 ov; ov.x = cvtpk(p0, p1); ov.y = cvtpk(p2, p3);
      *(uint2*)(op + (size_t)l31 * 512 + db * 32 + c * 8 + hl * 4) = ov;
    }
  }
}

// ---------------------------------------------------------------------------
// GELU(Po) + x residual + LayerNorm -> out f32 AND x2b bf16
__global__ __launch_bounds__(256) void ln_o(const u16* P, const float* x, const float* g, const float* B,
                                            float* out, u16* x2b){
  int w = threadIdx.x >> 6, l = threadIdx.x & 63;
  size_t r = (size_t)blockIdx.x * 4 + w;
  int n0 = l * 8;
  uint4 u = *(const uint4*)(P + r * 512 + n0);
  u32 ua[4] = {u.x, u.y, u.z, u.w};
  float4 x0 = *(const float4*)(x + r * 512 + n0);
  float4 x1 = *(const float4*)(x + r * 512 + n0 + 4);
  float xv[8] = {x0.x, x0.y, x0.z, x0.w, x1.x, x1.y, x1.z, x1.w};
  float v[8];
#pragma unroll
  for (int j = 0; j < 8; ++j){
    float pv = bf2f((u16)(ua[j >> 1] >> ((j & 1) * 16)));
    v[j] = gelu_exact(pv) + xv[j];
  }
  float s = 0.f, sq = 0.f;
#pragma unroll
  for (int j = 0; j < 8; ++j){ s += v[j]; sq += v[j] * v[j]; }
  for (int d = 1; d < 64; d <<= 1){ s += __shfl_xor(s, d); sq += __shfl_xor(sq, d); }
  float mean = s * (1.0f / 512.0f);
  float rstd = rsqrtf(sq * (1.0f / 512.0f) - mean * mean + 1e-5f);
  float y[8];
#pragma unroll
  for (int j = 0; j < 8; ++j) y[j] = (v[j] - mean) * rstd * g[n0 + j] + B[n0 + j];
  float4 o0, o1;
  o0.x = y[0]; o0.y = y[1]; o0.z = y[2]; o0.w = y[3];
  o1.x = y[4]; o1.y = y[5]; o1.z = y[6]; o1.w = y[7];
  *(float4*)(out + r * 512 + n0) = o0;
  *(float4*)(out + r * 512 + n0 + 4) = o1;
  uint4 ob; ob.x = pack2(y[0], y[1]); ob.y = pack2(y[2], y[3]);
  ob.z = pack2(y[4], y[5]); ob.w = pack2(y[6], y[7]);
  *(uint4*)(x2b + r * 512 + n0) = ob;
}

// ---------------------------------------------------------------------------
// w[row] = sum_n gelu(P1[row,n]) * W2[n] + b2  (full occupancy)
__global__ __launch_bounds__(256) void red_m(const u16* P, const float* W2, const float* b2, float* wv){
  int w = threadIdx.x >> 6, l = threadIdx.x & 63;
  size_t r = (size_t)blockIdx.x * 4 + w;
  int n0 = l * 8;
  uint4 u = *(const uint4*)(P + r * 512 + n0);
  u32 ua[4] = {u.x, u.y, u.z, u.w};
  float acc = 0.f;
#pragma unroll
  for (int j = 0; j < 8; ++j){
    float pv = bf2f((u16)(ua[j >> 1] >> ((j & 1) * 16)));
    acc += gelu_exact(pv) * W2[n0 + j];
  }
  for (int d = 1; d < 64; d <<= 1) acc += __shfl_xor(acc, d);
  if (l == 0) wv[r] = acc + b2[0];
}

__global__ __launch_bounds__(64) void fi_k(const float* wv, float* out){
  int b = blockIdx.x, l = threadIdx.x;
  float x[8]; float mx = -3.0e38f;
#pragma unroll
  for (int i = 0; i < 8; ++i){ x[i] = wv[b * 512 + i * 64 + l]; mx = fmaxf(mx, x[i]); }
  for (int d = 1; d < 64; d <<= 1) mx = fmaxf(mx, __shfl_xor(mx, d));
  float s = 0.f;
#pragma unroll
  for (int i = 0; i < 8; ++i){ x[i] = __expf(x[i] - mx); s += x[i]; }
  for (int d = 1; d < 64; d <<= 1) s += __shfl_xor(s, d);
  float inv = 1.0f / s;
#pragma unroll
  for (int i = 0; i < 8; ++i) out[b * 512 + i * 64 + l] = x[i] * inv;
}

// ---------------------------------------------------------------------------
extern "C" void kernel_launch(void* const* d_in, const int* in_sizes, int n_in,
                              void* d_out, int out_size, void* d_ws, size_t ws_size,
                              hipStream_t stream){
  const float* x    = (const float*)d_in[0];
  const float* Wq   = (const float*)d_in[1];
  const float* bq   = (const float*)d_in[2];
  const float* Wk   = (const float*)d_in[3];
  const float* bk   = (const float*)d_in[4];
  const float* Wv   = (const float*)d_in[5];
  const float* bv   = (const float*)d_in[6];
  const float* gq   = (const float*)d_in[7];
  const float* Bq   = (const float*)d_in[8];
  const float* gk   = (const float*)d_in[9];
  const float* Bk   = (const float*)d_in[10];
  const float* gv   = (const float*)d_in[11];
  const float* Bv   = (const float*)d_in[12];
  const float* Wo   = (const float*)d_in[13];
  const float* bo   = (const float*)d_in[14];
  const float* g_ln = (const float*)d_in[15];
  const float* b_ln = (const float*)d_in[16];
  const float* W1   = (const float*)d_in[17];
  const float* b1   = (const float*)d_in[18];
  const float* W2   = (const float*)d_in[19];
  const float* b2   = (const float*)d_in[20];
  float* out = (float*)d_out;

  char* ws = (char*)d_ws;
  u16*   WT    = (u16*)(ws);                         // 2,621,440 B
  float* biasS = (float*)(ws + 2621440);             // 6144
  float* gS    = (float*)(ws + 2627584);             // 6144
  float* BS    = (float*)(ws + 2633728);             // 6144
  u16*   xb    = (u16*)(ws + 2639872);               // 16,777,216 (reused as `at` after qkv gemm)
  u16*   at    = xb;
  u16*   P     = (u16*)(ws + 19417088);              // 50,331,648 ([16384][1536])
  u16*   Po    = P;                                  // [16384][512], P dead after attn
  u16*   x2b   = (u16*)((char*)P + 16777216);
  u16*   P1    = (u16*)((char*)P + 33554432);
  float* wvec  = (float*)(ws + 69748736);            // 65,536

  prep_all<<<9222, 256, 0, stream>>>(x, Wq, Wk, Wv, Wo, W1, bq, bk, bv,
                                     gq, Bq, gk, Bk, gv, Bv, WT, xb, biasS, gS, BS);

  gemm2<<<dim3(128, 12), 256, 0, stream>>>(xb, WT, biasS, P, 1536);       // fused QKV
  ln3<<<12288, 256, 0, stream>>>(P, gS, BS);                              // in-place, q pre-scaled

  attn_k<<<1024, 256, 0, stream>>>(P, at);

  gemm2<<<dim3(128, 4), 256, 0, stream>>>(at, WT + 3 * 262144, bo, Po, 512);
  ln_o<<<4096, 256, 0, stream>>>(Po, x, g_ln, b_ln, out, x2b);

  gemm2<<<dim3(128, 4), 256, 0, stream>>>(x2b, WT + 4 * 262144, b1, P1, 512);
  red_m<<<4096, 256, 0, stream>>>(P1, W2, b2, wvec);
  fi_k<<<32, 64, 0, stream>>>(wvec, out + 8388608);
}

// Round 17
// 154.730 us; speedup vs baseline: 1.0179x; 1.0031x over previous
//
#include <hip/hip_runtime.h>

typedef unsigned short u16;
typedef unsigned int   u32;
typedef __bf16 bf16x8 __attribute__((ext_vector_type(8)));
typedef float  f32x4  __attribute__((ext_vector_type(4)));
typedef float  f32x16 __attribute__((ext_vector_type(16)));

#define DEV __device__ __forceinline__

DEV u16 f2bf(float f){ u32 u = __builtin_bit_cast(u32, f); u += 0x7fffu + ((u >> 16) & 1u); return (u16)(u >> 16); }
DEV float bf2f(u16 h){ u32 u = ((u32)h) << 16; return __builtin_bit_cast(float, u); }
DEV u32 pack2(float a, float b){ return (u32)f2bf(a) | ((u32)f2bf(b) << 16); }
DEV f32x4 mfma16(bf16x8 a, bf16x8 b, f32x4 c){ return __builtin_amdgcn_mfma_f32_16x16x32_bf16(a, b, c, 0, 0, 0); }
DEV f32x16 mfma32(bf16x8 a, bf16x8 b, f32x16 c){ return __builtin_amdgcn_mfma_f32_32x32x16_bf16(a, b, c, 0, 0, 0); }
DEV float gelu_exact(float x){ return 0.5f * x * (1.0f + erff(x * 0.70710678118654752f)); }
DEV u32 cvtpk(float a, float b){ u32 r; asm("v_cvt_pk_bf16_f32 %0, %1, %2" : "=v"(r) : "v"(a), "v"(b)); return r; }
DEV void gload16(const void* g, void* l){
  __builtin_amdgcn_global_load_lds((const __attribute__((address_space(1))) void*)g,
                                   (__attribute__((address_space(3))) void*)l, 16, 0, 0);
}

// ---------------------------------------------------------------------------
// combined prep: [0,5120) prep_wt | [5120,9216) conv_x | [9216,9222) small
__global__ __launch_bounds__(256) void prep_all(const float* x, const float* Wq, const float* Wk,
                                                const float* Wv, const float* Wo, const float* W1,
                                                const float* bq, const float* bk, const float* bv,
                                                const float* gq, const float* Bq, const float* gk, const float* Bk,
                                                const float* gv, const float* Bv,
                                                u16* WT, u16* xb, float* biasS, float* gS, float* BS){
  int bid = blockIdx.x, t = threadIdx.x;
  if (bid < 5120){
    int i = bid * 256 + t;
    int z = i >> 18, r = i & 262143;               // r = kk*512 + n
    const float* W = (z==0)?Wq : (z==1)?Wk : (z==2)?Wv : (z==3)?Wo : W1;
    int n = r & 511, kk = r >> 9;
    WT[(size_t)z * 262144 + (size_t)n * 512 + kk] = f2bf(W[r]);
  } else if (bid < 9216){
    size_t i = ((size_t)(bid - 5120) * 256 + t) * 8;
    float4 f0 = *(const float4*)(x + i), f1 = *(const float4*)(x + i + 4);
    uint4 o; o.x = pack2(f0.x, f0.y); o.y = pack2(f0.z, f0.w);
    o.z = pack2(f1.x, f1.y); o.w = pack2(f1.z, f1.w);
    *(uint4*)(xb + i) = o;
  } else {
    int i = (bid - 9216) * 256 + t;                // 0..1535
    int z = i >> 9, n = i & 511;
    biasS[i] = (z==0) ? bq[n] : (z==1) ? bk[n] : bv[n];
    gS[i]    = (z==0) ? gq[n] * 0.125f : (z==1) ? gk[n] : gv[n];
    BS[i]    = (z==0) ? Bq[n] * 0.125f : (z==1) ? Bk[n] : Bv[n];
  }
}

// ---------------------------------------------------------------------------
// 2-phase GEMM (R5/R8 loop) + LDS-transposed coalesced epilogue.
// A[M,512]bf16 @ WT[N,512]^T + bias -> C bf16 (ldc). BM=BN=128, BK=64.
__global__ __launch_bounds__(256, 2) void gemm2(const u16* A, const u16* WT, const float* bias,
                                                u16* C, int ldc){
  int m0 = blockIdx.x * 128, n0 = blockIdx.y * 128;
  int t = threadIdx.x, l = t & 63, w = t >> 6;
  int wm = (w >> 1) * 64, wn = (w & 1) * 64;
  int l15 = l & 15, lg = l >> 4;
  __shared__ uint4 smem[4096];                     // 64KB: A dbuf [0,2048) | B dbuf [2048,4096)
  f32x4 acc[4][4] = {};

  auto stage = [&](int buf, int kt){
#pragma unroll
    for (int p = 0; p < 4; ++p){
      int sbase = w * 256 + p * 64;                // wave-uniform LDS base; lane offset = l*16B
      int slot = sbase + l;
      int r = slot >> 3, bb = (slot & 7) ^ (r & 7);  // pre-swizzled global source
      gload16(A  + (size_t)(m0 + r) * 512 + kt * 64 + bb * 8, &smem[buf * 1024 + sbase]);
      gload16(WT + (size_t)(n0 + r) * 512 + kt * 64 + bb * 8, &smem[2048 + buf * 1024 + sbase]);
    }
  };

  stage(0, 0);
  __syncthreads();                                 // tile 0 ready
  for (int kk = 0; kk < 8; ++kk){
    int cur = kk & 1;
    if (kk < 7) stage(cur ^ 1, kk + 1);            // prefetch hides under compute
#pragma unroll
    for (int kf = 0; kf < 2; ++kf){
      bf16x8 a[4], b[4];
      int bb = kf * 4 + lg;
#pragma unroll
      for (int mf = 0; mf < 4; ++mf){
        int r = wm + mf * 16 + l15;
        a[mf] = __builtin_bit_cast(bf16x8, smem[cur * 1024 + r * 8 + (bb ^ (r & 7))]);
      }
#pragma unroll
      for (int nf = 0; nf < 4; ++nf){
        int r = wn + nf * 16 + l15;
        b[nf] = __builtin_bit_cast(bf16x8, smem[2048 + cur * 1024 + r * 8 + (bb ^ (r & 7))]);
      }
#pragma unroll
      for (int mf = 0; mf < 4; ++mf)
#pragma unroll
        for (int nf = 0; nf < 4; ++nf)
          acc[mf][nf] = mfma16(a[mf], b[nf], acc[mf][nf]);
    }
    __syncthreads();                               // readers done + prefetch landed
  }

  // ---- epilogue: +bias, bf16 -> LDS tile [128][152] u16, then coalesced 16B stores.
  u16* tb = (u16*)smem;
#pragma unroll
  for (int nf = 0; nf < 4; ++nf){
    int cl = wn + nf * 16 + l15;
    float bv = bias[n0 + cl];
#pragma unroll
    for (int mf = 0; mf < 4; ++mf){
      int rl = wm + mf * 16 + lg * 4;
#pragma unroll
      for (int j = 0; j < 4; ++j)
        tb[(rl + j) * 152 + cl] = f2bf(acc[mf][nf][j] + bv);
    }
  }
  __syncthreads();
#pragma unroll
  for (int i = 0; i < 8; ++i){
    int row = i * 16 + (t >> 4), c8 = (t & 15) * 8;
    uint4 v = *(const uint4*)&tb[row * 152 + c8];
    *(uint4*)(C + (size_t)(m0 + row) * ldc + n0 + c8) = v;
  }
}

// ---------------------------------------------------------------------------
// fused LN over the 3 projection segments of P[16384][1536], in place.
__global__ __launch_bounds__(256) void ln3(u16* P, const float* gS, const float* BS){
  int w = threadIdx.x >> 6, l = threadIdx.x & 63;
  int z = blockIdx.x >> 12;
  size_t r = (size_t)(blockIdx.x & 4095) * 4 + w;
  u16* row = P + r * 1536 + z * 512;
  int n0 = l * 8, ng = z * 512 + n0;
  uint4 u = *(const uint4*)(row + n0);
  u32 ua[4] = {u.x, u.y, u.z, u.w};
  float v[8];
#pragma unroll
  for (int j = 0; j < 8; ++j) v[j] = bf2f((u16)(ua[j >> 1] >> ((j & 1) * 16)));
  float s = 0.f, sq = 0.f;
#pragma unroll
  for (int j = 0; j < 8; ++j){ s += v[j]; sq += v[j] * v[j]; }
  for (int d = 1; d < 64; d <<= 1){ s += __shfl_xor(s, d); sq += __shfl_xor(sq, d); }
  float mean = s * (1.0f / 512.0f);
  float rstd = rsqrtf(sq * (1.0f / 512.0f) - mean * mean + 1e-5f);
  u32 o[4];
#pragma unroll
  for (int jj = 0; jj < 4; ++jj){
    float y0 = (v[2*jj]   - mean) * rstd * gS[ng + 2*jj]   + BS[ng + 2*jj];
    float y1 = (v[2*jj+1] - mean) * rstd * gS[ng + 2*jj+1] + BS[ng + 2*jj+1];
    o[jj] = pack2(y0, y1);
  }
  uint4 ov; ov.x = o[0]; ov.y = o[1]; ov.z = o[2]; ov.w = o[3];
  *(uint4*)(row + n0) = ov;
}

// ---------------------------------------------------------------------------
// Flash attention, 8 waves x 32 q-rows (256 q-rows/block): K/V staging shared
// by 2x the q-rows vs the 4-wave variant. Per-wave math identical (32x32x16
// swapped QK^T, no-max softmax, cvt_pk+permlane P->A-frag).
__global__ __launch_bounds__(512, 3) void attn_k(const u16* qkv, u16* o){
  int bid = blockIdx.x;                            // 512 blocks; XCD-bijective swizzle (512%8==0)
  int swz = (bid & 7) * 64 + (bid >> 3);
  int qt = swz & 1, h = (swz >> 1) & 7, b = swz >> 4;
  int t = threadIdx.x, l = t & 63, w = t >> 6, l31 = l & 31, hl = l >> 5;
  __shared__ uint4 Ks[2][512];                     // [64 s][8 blk] swizzled (blk ^ (s&7))
  __shared__ uint4 Vt[2][512];                     // V^T [64 d][8 blk] swizzled

  int qrow0 = b * 512 + qt * 256 + w * 32;
  const u16* qp = qkv + (size_t)qrow0 * 1536 + h * 64;
  const u16* kp = qkv + (size_t)(b * 512) * 1536 + 512  + h * 64;
  const u16* vp = qkv + (size_t)(b * 512) * 1536 + 1024 + h * 64;

  bf16x8 bq[4];
#pragma unroll
  for (int tp = 0; tp < 4; ++tp)
    bq[tp] = *(const bf16x8*)(qp + (size_t)l31 * 1536 + tp * 16 + hl * 8);

  int dg = t & 15, sgrp = t >> 4;                  // sgrp in [0,32): 2 s-rows each
  int bs = sgrp >> 2, hq = sgrp & 3;
  const u32 sel0 = 0x05040100u, sel1 = 0x07060302u;
  uint2 vld0, vld1;

  // ---- prologue: stage tile 0 (K via gload_lds: 1 per thread; V reg-staged)
  {
    int r = t >> 3, bb = (t & 7) ^ (r & 7);
    gload16(kp + (size_t)r * 1536 + bb * 8, &Ks[0][w * 64]);
  }
  vld0 = *(const uint2*)(vp + (size_t)(sgrp * 2 + 0) * 1536 + dg * 4);
  vld1 = *(const uint2*)(vp + (size_t)(sgrp * 2 + 1) * 1536 + dg * 4);
  {
    u16* base = (u16*)&Vt[0][0];
#pragma unroll
    for (int j = 0; j < 4; ++j){
      u32 word = (j < 2) ? __builtin_amdgcn_perm(vld1.x, vld0.x, (j & 1) ? sel1 : sel0)
                         : __builtin_amdgcn_perm(vld1.y, vld0.y, (j & 1) ? sel1 : sel0);
      int d = dg * 4 + j;
      *(u32*)(base + d * 64 + (bs ^ (d & 7)) * 8 + hq * 2) = word;
    }
  }
  __syncthreads();

  f32x16 Od0 = {}, Od1 = {};
  float lsum = 0.f;

  for (int tile = 0; tile < 8; ++tile){
    int cur = tile & 1;
    if (tile < 7){
      int s0n = (tile + 1) * 64;
      {
        int r = t >> 3, bb = (t & 7) ^ (r & 7);
        gload16(kp + (size_t)(s0n + r) * 1536 + bb * 8, &Ks[cur ^ 1][w * 64]);
      }
      vld0 = *(const uint2*)(vp + (size_t)(s0n + sgrp * 2 + 0) * 1536 + dg * 4);
      vld1 = *(const uint2*)(vp + (size_t)(s0n + sgrp * 2 + 1) * 1536 + dg * 4);
    }

    f32x16 S0 = {}, S1 = {};
#pragma unroll
    for (int tp = 0; tp < 4; ++tp){
      int bb = 2 * tp + hl;
      int r0 = l31, r1 = 32 + l31;
      bf16x8 k0 = __builtin_bit_cast(bf16x8, Ks[cur][r0 * 8 + (bb ^ (r0 & 7))]);
      bf16x8 k1 = __builtin_bit_cast(bf16x8, Ks[cur][r1 * 8 + (bb ^ (r1 & 7))]);
      S0 = mfma32(k0, bq[tp], S0);
      S1 = mfma32(k1, bq[tp], S1);
    }

    u32 W0[8], W1[8];
#pragma unroll
    for (int m = 0; m < 8; ++m){
      float e0 = __expf(S0[2 * m]), e1 = __expf(S0[2 * m + 1]);
      float f0 = __expf(S1[2 * m]), f1 = __expf(S1[2 * m + 1]);
      lsum += (e0 + e1) + (f0 + f1);
      W0[m] = cvtpk(e0, e1);
      W1[m] = cvtpk(f0, f1);
    }

    bf16x8 pa[4];
#pragma unroll
    for (int tt = 0; tt < 4; ++tt){
      int m0 = (tt & 1) * 4;
      u32 a0 = (tt < 2) ? W0[m0]     : W1[m0];
      u32 c0 = (tt < 2) ? W0[m0 + 2] : W1[m0 + 2];
      u32 a1 = (tt < 2) ? W0[m0 + 1] : W1[m0 + 1];
      u32 c1 = (tt < 2) ? W0[m0 + 3] : W1[m0 + 3];
      asm volatile("v_permlane32_swap_b32 %0, %1" : "+v"(a0), "+v"(c0));
      asm volatile("v_permlane32_swap_b32 %0, %1" : "+v"(a1), "+v"(c1));
      uint4 pf; pf.x = a0; pf.y = a1; pf.z = c0; pf.w = c1;
      pa[tt] = __builtin_bit_cast(bf16x8, pf);
    }

#pragma unroll
    for (int tt = 0; tt < 4; ++tt){
      int bb = 2 * tt + hl;
      int r0 = l31, r1 = 32 + l31;
      bf16x8 v0 = __builtin_bit_cast(bf16x8, Vt[cur][r0 * 8 + (bb ^ (r0 & 7))]);
      bf16x8 v1 = __builtin_bit_cast(bf16x8, Vt[cur][r1 * 8 + (bb ^ (r1 & 7))]);
      Od0 = mfma32(v0, pa[tt], Od0);
      Od1 = mfma32(v1, pa[tt], Od1);
    }

    if (tile < 7){
      u16* base = (u16*)&Vt[cur ^ 1][0];
#pragma unroll
      for (int j = 0; j < 4; ++j){
        u32 word = (j < 2) ? __builtin_amdgcn_perm(vld1.x, vld0.x, (j & 1) ? sel1 : sel0)
                           : __builtin_amdgcn_perm(vld1.y, vld0.y, (j & 1) ? sel1 : sel0);
        int d = dg * 4 + j;
        *(u32*)(base + d * 64 + (bs ^ (d & 7)) * 8 + hq * 2) = word;
      }
    }
    __syncthreads();
  }

  float inv = 1.0f / (lsum + __shfl_xor(lsum, 32));
  u16* op = o + (size_t)qrow0 * 512 + h * 64;
#pragma unroll
  for (int db = 0; db < 2; ++db){
#pragma unroll
    for (int c = 0; c < 4; ++c){
      float p0 = ((db ? Od1 : Od0)[4 * c + 0]) * inv;
      float p1 = ((db ? Od1 : Od0)[4 * c + 1]) * inv;
      float p2 = ((db ? Od1 : Od0)[4 * c + 2]) * inv;
      float p3 = ((db ? Od1 : Od0)[4 * c + 3]) * inv;
      uint2 ov; ov.x = cvtpk(p0, p1); ov.y = cvtpk(p2, p3);
      *(uint2*)(op + (size_t)l31 * 512 + db * 32 + c * 8 + hl * 4) = ov;
    }
  }
}

// ---------------------------------------------------------------------------
// GELU(Po) + x residual + LayerNorm -> out f32 AND x2b bf16
__global__ __launch_bounds__(256) void ln_o(const u16* P, const float* x, const float* g, const float* B,
                                            float* out, u16* x2b){
  int w = threadIdx.x >> 6, l = threadIdx.x & 63;
  size_t r = (size_t)blockIdx.x * 4 + w;
  int n0 = l * 8;
  uint4 u = *(const uint4*)(P + r * 512 + n0);
  u32 ua[4] = {u.x, u.y, u.z, u.w};
  float4 x0 = *(const float4*)(x + r * 512 + n0);
  float4 x1 = *(const float4*)(x + r * 512 + n0 + 4);
  float xv[8] = {x0.x, x0.y, x0.z, x0.w, x1.x, x1.y, x1.z, x1.w};
  float v[8];
#pragma unroll
  for (int j = 0; j < 8; ++j){
    float pv = bf2f((u16)(ua[j >> 1] >> ((j & 1) * 16)));
    v[j] = gelu_exact(pv) + xv[j];
  }
  float s = 0.f, sq = 0.f;
#pragma unroll
  for (int j = 0; j < 8; ++j){ s += v[j]; sq += v[j] * v[j]; }
  for (int d = 1; d < 64; d <<= 1){ s += __shfl_xor(s, d); sq += __shfl_xor(sq, d); }
  float mean = s * (1.0f / 512.0f);
  float rstd = rsqrtf(sq * (1.0f / 512.0f) - mean * mean + 1e-5f);
  float y[8];
#pragma unroll
  for (int j = 0; j < 8; ++j) y[j] = (v[j] - mean) * rstd * g[n0 + j] + B[n0 + j];
  float4 o0, o1;
  o0.x = y[0]; o0.y = y[1]; o0.z = y[2]; o0.w = y[3];
  o1.x = y[4]; o1.y = y[5]; o1.z = y[6]; o1.w = y[7];
  *(float4*)(out + r * 512 + n0) = o0;
  *(float4*)(out + r * 512 + n0 + 4) = o1;
  uint4 ob; ob.x = pack2(y[0], y[1]); ob.y = pack2(y[2], y[3]);
  ob.z = pack2(y[4], y[5]); ob.w = pack2(y[6], y[7]);
  *(uint4*)(x2b + r * 512 + n0) = ob;
}

// ---------------------------------------------------------------------------
// w[row] = sum_n gelu(P1[row,n]) * W2[n] + b2  (full occupancy)
__global__ __launch_bounds__(256) void red_m(const u16* P, const float* W2, const float* b2, float* wv){
  int w = threadIdx.x >> 6, l = threadIdx.x & 63;
  size_t r = (size_t)blockIdx.x * 4 + w;
  int n0 = l * 8;
  uint4 u = *(const uint4*)(P + r * 512 + n0);
  u32 ua[4] = {u.x, u.y, u.z, u.w};
  float acc = 0.f;
#pragma unroll
  for (int j = 0; j < 8; ++j){
    float pv = bf2f((u16)(ua[j >> 1] >> ((j & 1) * 16)));
    acc += gelu_exact(pv) * W2[n0 + j];
  }
  for (int d = 1; d < 64; d <<= 1) acc += __shfl_xor(acc, d);
  if (l == 0) wv[r] = acc + b2[0];
}

__global__ __launch_bounds__(64) void fi_k(const float* wv, float* out){
  int b = blockIdx.x, l = threadIdx.x;
  float x[8]; float mx = -3.0e38f;
#pragma unroll
  for (int i = 0; i < 8; ++i){ x[i] = wv[b * 512 + i * 64 + l]; mx = fmaxf(mx, x[i]); }
  for (int d = 1; d < 64; d <<= 1) mx = fmaxf(mx, __shfl_xor(mx, d));
  float s = 0.f;
#pragma unroll
  for (int i = 0; i < 8; ++i){ x[i] = __expf(x[i] - mx); s += x[i]; }
  for (int d = 1; d < 64; d <<= 1) s += __shfl_xor(s, d);
  float inv = 1.0f / s;
#pragma unroll
  for (int i = 0; i < 8; ++i) out[b * 512 + i * 64 + l] = x[i] * inv;
}

// ---------------------------------------------------------------------------
extern "C" void kernel_launch(void* const* d_in, const int* in_sizes, int n_in,
                              void* d_out, int out_size, void* d_ws, size_t ws_size,
                              hipStream_t stream){
  const float* x    = (const float*)d_in[0];
  const float* Wq   = (const float*)d_in[1];
  const float* bq   = (const float*)d_in[2];
  const float* Wk   = (const float*)d_in[3];
  const float* bk   = (const float*)d_in[4];
  const float* Wv   = (const float*)d_in[5];
  const float* bv   = (const float*)d_in[6];
  const float* gq   = (const float*)d_in[7];
  const float* Bq   = (const float*)d_in[8];
  const float* gk   = (const float*)d_in[9];
  const float* Bk   = (const float*)d_in[10];
  const float* gv   = (const float*)d_in[11];
  const float* Bv   = (const float*)d_in[12];
  const float* Wo   = (const float*)d_in[13];
  const float* bo   = (const float*)d_in[14];
  const float* g_ln = (const float*)d_in[15];
  const float* b_ln = (const float*)d_in[16];
  const float* W1   = (const float*)d_in[17];
  const float* b1   = (const float*)d_in[18];
  const float* W2   = (const float*)d_in[19];
  const float* b2   = (const float*)d_in[20];
  float* out = (float*)d_out;

  char* ws = (char*)d_ws;
  u16*   WT    = (u16*)(ws);                         // 2,621,440 B
  float* biasS = (float*)(ws + 2621440);             // 6144
  float* gS    = (float*)(ws + 2627584);             // 6144
  float* BS    = (float*)(ws + 2633728);             // 6144
  u16*   xb    = (u16*)(ws + 2639872);               // 16,777,216 (reused as `at` after qkv gemm)
  u16*   at    = xb;
  u16*   P     = (u16*)(ws + 19417088);              // 50,331,648 ([16384][1536])
  u16*   Po    = P;                                  // [16384][512], P dead after attn
  u16*   x2b   = (u16*)((char*)P + 16777216);
  u16*   P1    = (u16*)((char*)P + 33554432);
  float* wvec  = (float*)(ws + 69748736);            // 65,536

  prep_all<<<9222, 256, 0, stream>>>(x, Wq, Wk, Wv, Wo, W1, bq, bk, bv,
                                     gq, Bq, gk, Bk, gv, Bv, WT, xb, biasS, gS, BS);

  gemm2<<<dim3(128, 12), 256, 0, stream>>>(xb, WT, biasS, P, 1536);       // fused QKV
  ln3<<<12288, 256, 0, stream>>>(P, gS, BS);                              // in-place, q pre-scaled

  attn_k<<<512, 512, 0, stream>>>(P, at);

  gemm2<<<dim3(128, 4), 256, 0, stream>>>(at, WT + 3 * 262144, bo, Po, 512);
  ln_o<<<4096, 256, 0, stream>>>(Po, x, g_ln, b_ln, out, x2b);

  gemm2<<<dim3(128, 4), 256, 0, stream>>>(x2b, WT + 4 * 262144, b1, P1, 512);
  red_m<<<4096, 256, 0, stream>>>(P1, W2, b2, wvec);
  fi_k<<<32, 64, 0, stream>>>(wvec, out + 8388608);
}

// Round 18
// 154.600 us; speedup vs baseline: 1.0188x; 1.0008x over previous
//
#include <hip/hip_runtime.h>

typedef unsigned short u16;
typedef unsigned int   u32;
typedef __bf16 bf16x8 __attribute__((ext_vector_type(8)));
typedef float  f32x4  __attribute__((ext_vector_type(4)));
typedef float  f32x16 __attribute__((ext_vector_type(16)));

#define DEV __device__ __forceinline__

DEV u16 f2bf(float f){ u32 u = __builtin_bit_cast(u32, f); u += 0x7fffu + ((u >> 16) & 1u); return (u16)(u >> 16); }
DEV float bf2f(u16 h){ u32 u = ((u32)h) << 16; return __builtin_bit_cast(float, u); }
DEV u32 pack2(float a, float b){ return (u32)f2bf(a) | ((u32)f2bf(b) << 16); }
DEV f32x4 mfma16(bf16x8 a, bf16x8 b, f32x4 c){ return __builtin_amdgcn_mfma_f32_16x16x32_bf16(a, b, c, 0, 0, 0); }
DEV f32x16 mfma32(bf16x8 a, bf16x8 b, f32x16 c){ return __builtin_amdgcn_mfma_f32_32x32x16_bf16(a, b, c, 0, 0, 0); }
DEV float gelu_exact(float x){ return 0.5f * x * (1.0f + erff(x * 0.70710678118654752f)); }
DEV u32 cvtpk(float a, float b){ u32 r; asm("v_cvt_pk_bf16_f32 %0, %1, %2" : "=v"(r) : "v"(a), "v"(b)); return r; }
DEV void gload16(const void* g, void* l){
  __builtin_amdgcn_global_load_lds((const __attribute__((address_space(1))) void*)g,
                                   (__attribute__((address_space(3))) void*)l, 16, 0, 0);
}

// ---------------------------------------------------------------------------
// combined prep: [0,5120) prep_wt | [5120,9216) conv_x | [9216,9222) small
__global__ __launch_bounds__(256) void prep_all(const float* x, const float* Wq, const float* Wk,
                                                const float* Wv, const float* Wo, const float* W1,
                                                const float* bq, const float* bk, const float* bv,
                                                const float* gq, const float* Bq, const float* gk, const float* Bk,
                                                const float* gv, const float* Bv,
                                                u16* WT, u16* xb, float* biasS, float* gS, float* BS){
  int bid = blockIdx.x, t = threadIdx.x;
  if (bid < 5120){
    int i = bid * 256 + t;
    int z = i >> 18, r = i & 262143;               // r = kk*512 + n
    const float* W = (z==0)?Wq : (z==1)?Wk : (z==2)?Wv : (z==3)?Wo : W1;
    int n = r & 511, kk = r >> 9;
    WT[(size_t)z * 262144 + (size_t)n * 512 + kk] = f2bf(W[r]);
  } else if (bid < 9216){
    size_t i = ((size_t)(bid - 5120) * 256 + t) * 8;
    float4 f0 = *(const float4*)(x + i), f1 = *(const float4*)(x + i + 4);
    uint4 o; o.x = pack2(f0.x, f0.y); o.y = pack2(f0.z, f0.w);
    o.z = pack2(f1.x, f1.y); o.w = pack2(f1.z, f1.w);
    *(uint4*)(xb + i) = o;
  } else {
    int i = (bid - 9216) * 256 + t;                // 0..1535
    int z = i >> 9, n = i & 511;
    biasS[i] = (z==0) ? bq[n] : (z==1) ? bk[n] : bv[n];
    gS[i]    = (z==0) ? gq[n] * 0.125f : (z==1) ? gk[n] : gv[n];
    BS[i]    = (z==0) ? Bq[n] * 0.125f : (z==1) ? Bk[n] : Bv[n];
  }
}

// ---------------------------------------------------------------------------
// 2-phase GEMM (R5/R8 loop) + LDS-transposed coalesced epilogue.
// A[M,512]bf16 @ WT[N,512]^T + bias -> C bf16 (ldc). BM=BN=128, BK=64.
__global__ __launch_bounds__(256, 2) void gemm2(const u16* A, const u16* WT, const float* bias,
                                                u16* C, int ldc){
  int m0 = blockIdx.x * 128, n0 = blockIdx.y * 128;
  int t = threadIdx.x, l = t & 63, w = t >> 6;
  int wm = (w >> 1) * 64, wn = (w & 1) * 64;
  int l15 = l & 15, lg = l >> 4;
  __shared__ uint4 smem[4096];                     // 64KB: A dbuf [0,2048) | B dbuf [2048,4096)
  f32x4 acc[4][4] = {};

  auto stage = [&](int buf, int kt){
#pragma unroll
    for (int p = 0; p < 4; ++p){
      int sbase = w * 256 + p * 64;                // wave-uniform LDS base; lane offset = l*16B
      int slot = sbase + l;
      int r = slot >> 3, bb = (slot & 7) ^ (r & 7);  // pre-swizzled global source
      gload16(A  + (size_t)(m0 + r) * 512 + kt * 64 + bb * 8, &smem[buf * 1024 + sbase]);
      gload16(WT + (size_t)(n0 + r) * 512 + kt * 64 + bb * 8, &smem[2048 + buf * 1024 + sbase]);
    }
  };

  stage(0, 0);
  __syncthreads();                                 // tile 0 ready
  for (int kk = 0; kk < 8; ++kk){
    int cur = kk & 1;
    if (kk < 7) stage(cur ^ 1, kk + 1);            // prefetch hides under compute
#pragma unroll
    for (int kf = 0; kf < 2; ++kf){
      bf16x8 a[4], b[4];
      int bb = kf * 4 + lg;
#pragma unroll
      for (int mf = 0; mf < 4; ++mf){
        int r = wm + mf * 16 + l15;
        a[mf] = __builtin_bit_cast(bf16x8, smem[cur * 1024 + r * 8 + (bb ^ (r & 7))]);
      }
#pragma unroll
      for (int nf = 0; nf < 4; ++nf){
        int r = wn + nf * 16 + l15;
        b[nf] = __builtin_bit_cast(bf16x8, smem[2048 + cur * 1024 + r * 8 + (bb ^ (r & 7))]);
      }
#pragma unroll
      for (int mf = 0; mf < 4; ++mf)
#pragma unroll
        for (int nf = 0; nf < 4; ++nf)
          acc[mf][nf] = mfma16(a[mf], b[nf], acc[mf][nf]);
    }
    __syncthreads();                               // readers done + prefetch landed
  }

  // ---- epilogue: +bias, bf16 -> LDS tile [128][152] u16, then coalesced 16B stores.
  u16* tb = (u16*)smem;
#pragma unroll
  for (int nf = 0; nf < 4; ++nf){
    int cl = wn + nf * 16 + l15;
    float bv = bias[n0 + cl];
#pragma unroll
    for (int mf = 0; mf < 4; ++mf){
      int rl = wm + mf * 16 + lg * 4;
#pragma unroll
      for (int j = 0; j < 4; ++j)
        tb[(rl + j) * 152 + cl] = f2bf(acc[mf][nf][j] + bv);
    }
  }
  __syncthreads();
#pragma unroll
  for (int i = 0; i < 8; ++i){
    int row = i * 16 + (t >> 4), c8 = (t & 15) * 8;
    uint4 v = *(const uint4*)&tb[row * 152 + c8];
    *(uint4*)(C + (size_t)(m0 + row) * ldc + n0 + c8) = v;
  }
}

// ---------------------------------------------------------------------------
// fused LN over the 3 projection segments of P[16384][1536], in place.
__global__ __launch_bounds__(256) void ln3(u16* P, const float* gS, const float* BS){
  int w = threadIdx.x >> 6, l = threadIdx.x & 63;
  int z = blockIdx.x >> 12;
  size_t r = (size_t)(blockIdx.x & 4095) * 4 + w;
  u16* row = P + r * 1536 + z * 512;
  int n0 = l * 8, ng = z * 512 + n0;
  uint4 u = *(const uint4*)(row + n0);
  u32 ua[4] = {u.x, u.y, u.z, u.w};
  float v[8];
#pragma unroll
  for (int j = 0; j < 8; ++j) v[j] = bf2f((u16)(ua[j >> 1] >> ((j & 1) * 16)));
  float s = 0.f, sq = 0.f;
#pragma unroll
  for (int j = 0; j < 8; ++j){ s += v[j]; sq += v[j] * v[j]; }
  for (int d = 1; d < 64; d <<= 1){ s += __shfl_xor(s, d); sq += __shfl_xor(sq, d); }
  float mean = s * (1.0f / 512.0f);
  float rstd = rsqrtf(sq * (1.0f / 512.0f) - mean * mean + 1e-5f);
  u32 o[4];
#pragma unroll
  for (int jj = 0; jj < 4; ++jj){
    float y0 = (v[2*jj]   - mean) * rstd * gS[ng + 2*jj]   + BS[ng + 2*jj];
    float y1 = (v[2*jj+1] - mean) * rstd * gS[ng + 2*jj+1] + BS[ng + 2*jj+1];
    o[jj] = pack2(y0, y1);
  }
  uint4 ov; ov.x = o[0]; ov.y = o[1]; ov.z = o[2]; ov.w = o[3];
  *(uint4*)(row + n0) = ov;
}

// ---------------------------------------------------------------------------
// Flash attention, 8 waves x 32 q-rows (256 q-rows/block): K/V staging shared
// by 2x the q-rows vs the 4-wave variant. Per-wave math identical (32x32x16
// swapped QK^T, no-max softmax, cvt_pk+permlane P->A-frag).
__global__ __launch_bounds__(512, 3) void attn_k(const u16* qkv, u16* o){
  int bid = blockIdx.x;                            // 512 blocks; XCD-bijective swizzle (512%8==0)
  int swz = (bid & 7) * 64 + (bid >> 3);
  int qt = swz & 1, h = (swz >> 1) & 7, b = swz >> 4;
  int t = threadIdx.x, l = t & 63, w = t >> 6, l31 = l & 31, hl = l >> 5;
  __shared__ uint4 Ks[2][512];                     // [64 s][8 blk] swizzled (blk ^ (s&7))
  __shared__ uint4 Vt[2][512];                     // V^T [64 d][8 blk] swizzled

  int qrow0 = b * 512 + qt * 256 + w * 32;
  const u16* qp = qkv + (size_t)qrow0 * 1536 + h * 64;
  const u16* kp = qkv + (size_t)(b * 512) * 1536 + 512  + h * 64;
  const u16* vp = qkv + (size_t)(b * 512) * 1536 + 1024 + h * 64;

  bf16x8 bq[4];
#pragma unroll
  for (int tp = 0; tp < 4; ++tp)
    bq[tp] = *(const bf16x8*)(qp + (size_t)l31 * 1536 + tp * 16 + hl * 8);

  int dg = t & 15, sgrp = t >> 4;                  // sgrp in [0,32): 2 s-rows each
  int bs = sgrp >> 2, hq = sgrp & 3;
  const u32 sel0 = 0x05040100u, sel1 = 0x07060302u;
  uint2 vld0, vld1;

  // ---- prologue: stage tile 0 (K via gload_lds: 1 per thread; V reg-staged)
  {
    int r = t >> 3, bb = (t & 7) ^ (r & 7);
    gload16(kp + (size_t)r * 1536 + bb * 8, &Ks[0][w * 64]);
  }
  vld0 = *(const uint2*)(vp + (size_t)(sgrp * 2 + 0) * 1536 + dg * 4);
  vld1 = *(const uint2*)(vp + (size_t)(sgrp * 2 + 1) * 1536 + dg * 4);
  {
    u16* base = (u16*)&Vt[0][0];
#pragma unroll
    for (int j = 0; j < 4; ++j){
      u32 word = (j < 2) ? __builtin_amdgcn_perm(vld1.x, vld0.x, (j & 1) ? sel1 : sel0)
                         : __builtin_amdgcn_perm(vld1.y, vld0.y, (j & 1) ? sel1 : sel0);
      int d = dg * 4 + j;
      *(u32*)(base + d * 64 + (bs ^ (d & 7)) * 8 + hq * 2) = word;
    }
  }
  __syncthreads();

  f32x16 Od0 = {}, Od1 = {};
  float lsum = 0.f;

  for (int tile = 0; tile < 8; ++tile){
    int cur = tile & 1;
    if (tile < 7){
      int s0n = (tile + 1) * 64;
      {
        int r = t >> 3, bb = (t & 7) ^ (r & 7);
        gload16(kp + (size_t)(s0n + r) * 1536 + bb * 8, &Ks[cur ^ 1][w * 64]);
      }
      vld0 = *(const uint2*)(vp + (size_t)(s0n + sgrp * 2 + 0) * 1536 + dg * 4);
      vld1 = *(const uint2*)(vp + (size_t)(s0n + sgrp * 2 + 1) * 1536 + dg * 4);
    }

    f32x16 S0 = {}, S1 = {};
#pragma unroll
    for (int tp = 0; tp < 4; ++tp){
      int bb = 2 * tp + hl;
      int r0 = l31, r1 = 32 + l31;
      bf16x8 k0 = __builtin_bit_cast(bf16x8, Ks[cur][r0 * 8 + (bb ^ (r0 & 7))]);
      bf16x8 k1 = __builtin_bit_cast(bf16x8, Ks[cur][r1 * 8 + (bb ^ (r1 & 7))]);
      S0 = mfma32(k0, bq[tp], S0);
      S1 = mfma32(k1, bq[tp], S1);
    }

    u32 W0[8], W1[8];
#pragma unroll
    for (int m = 0; m < 8; ++m){
      float e0 = __expf(S0[2 * m]), e1 = __expf(S0[2 * m + 1]);
      float f0 = __expf(S1[2 * m]), f1 = __expf(S1[2 * m + 1]);
      lsum += (e0 + e1) + (f0 + f1);
      W0[m] = cvtpk(e0, e1);
      W1[m] = cvtpk(f0, f1);
    }

    bf16x8 pa[4];
#pragma unroll
    for (int tt = 0; tt < 4; ++tt){
      int m0 = (tt & 1) * 4;
      u32 a0 = (tt < 2) ? W0[m0]     : W1[m0];
      u32 c0 = (tt < 2) ? W0[m0 + 2] : W1[m0 + 2];
      u32 a1 = (tt < 2) ? W0[m0 + 1] : W1[m0 + 1];
      u32 c1 = (tt < 2) ? W0[m0 + 3] : W1[m0 + 3];
      asm volatile("v_permlane32_swap_b32 %0, %1" : "+v"(a0), "+v"(c0));
      asm volatile("v_permlane32_swap_b32 %0, %1" : "+v"(a1), "+v"(c1));
      uint4 pf; pf.x = a0; pf.y = a1; pf.z = c0; pf.w = c1;
      pa[tt] = __builtin_bit_cast(bf16x8, pf);
    }

#pragma unroll
    for (int tt = 0; tt < 4; ++tt){
      int bb = 2 * tt + hl;
      int r0 = l31, r1 = 32 + l31;
      bf16x8 v0 = __builtin_bit_cast(bf16x8, Vt[cur][r0 * 8 + (bb ^ (r0 & 7))]);
      bf16x8 v1 = __builtin_bit_cast(bf16x8, Vt[cur][r1 * 8 + (bb ^ (r1 & 7))]);
      Od0 = mfma32(v0, pa[tt], Od0);
      Od1 = mfma32(v1, pa[tt], Od1);
    }

    if (tile < 7){
      u16* base = (u16*)&Vt[cur ^ 1][0];
#pragma unroll
      for (int j = 0; j < 4; ++j){
        u32 word = (j < 2) ? __builtin_amdgcn_perm(vld1.x, vld0.x, (j & 1) ? sel1 : sel0)
                           : __builtin_amdgcn_perm(vld1.y, vld0.y, (j & 1) ? sel1 : sel0);
        int d = dg * 4 + j;
        *(u32*)(base + d * 64 + (bs ^ (d & 7)) * 8 + hq * 2) = word;
      }
    }
    __syncthreads();
  }

  float inv = 1.0f / (lsum + __shfl_xor(lsum, 32));
  u16* op = o + (size_t)qrow0 * 512 + h * 64;
#pragma unroll
  for (int db = 0; db < 2; ++db){
#pragma unroll
    for (int c = 0; c < 4; ++c){
      float p0 = ((db ? Od1 : Od0)[4 * c + 0]) * inv;
      float p1 = ((db ? Od1 : Od0)[4 * c + 1]) * inv;
      float p2 = ((db ? Od1 : Od0)[4 * c + 2]) * inv;
      float p3 = ((db ? Od1 : Od0)[4 * c + 3]) * inv;
      uint2 ov; ov.x = cvtpk(p0, p1); ov.y = cvtpk(p2, p3);
      *(uint2*)(op + (size_t)l31 * 512 + db * 32 + c * 8 + hl * 4) = ov;
    }
  }
}

// ---------------------------------------------------------------------------
// GELU(Po) + x residual + LayerNorm -> out f32 AND x2b bf16
__global__ __launch_bounds__(256) void ln_o(const u16* P, const float* x, const float* g, const float* B,
                                            float* out, u16* x2b){
  int w = threadIdx.x >> 6, l = threadIdx.x & 63;
  size_t r = (size_t)blockIdx.x * 4 + w;
  int n0 = l * 8;
  uint4 u = *(const uint4*)(P + r * 512 + n0);
  u32 ua[4] = {u.x, u.y, u.z, u.w};
  float4 x0 = *(const float4*)(x + r * 512 + n0);
  float4 x1 = *(const float4*)(x + r * 512 + n0 + 4);
  float xv[8] = {x0.x, x0.y, x0.z, x0.w, x1.x, x1.y, x1.z, x1.w};
  float v[8];
#pragma unroll
  for (int j = 0; j < 8; ++j){
    float pv = bf2f((u16)(ua[j >> 1] >> ((j & 1) * 16)));
    v[j] = gelu_exact(pv) + xv[j];
  }
  float s = 0.f, sq = 0.f;
#pragma unroll
  for (int j = 0; j < 8; ++j){ s += v[j]; sq += v[j] * v[j]; }
  for (int d = 1; d < 64; d <<= 1){ s += __shfl_xor(s, d); sq += __shfl_xor(sq, d); }
  float mean = s * (1.0f / 512.0f);
  float rstd = rsqrtf(sq * (1.0f / 512.0f) - mean * mean + 1e-5f);
  float y[8];
#pragma unroll
  for (int j = 0; j < 8; ++j) y[j] = (v[j] - mean) * rstd * g[n0 + j] + B[n0 + j];
  float4 o0, o1;
  o0.x = y[0]; o0.y = y[1]; o0.z = y[2]; o0.w = y[3];
  o1.x = y[4]; o1.y = y[5]; o1.z = y[6]; o1.w = y[7];
  *(float4*)(out + r * 512 + n0) = o0;
  *(float4*)(out + r * 512 + n0 + 4) = o1;
  uint4 ob; ob.x = pack2(y[0], y[1]); ob.y = pack2(y[2], y[3]);
  ob.z = pack2(y[4], y[5]); ob.w = pack2(y[6], y[7]);
  *(uint4*)(x2b + r * 512 + n0) = ob;
}

// ---------------------------------------------------------------------------
// w[row] = sum_n gelu(P1[row,n]) * W2[n] + b2  (full occupancy)
__global__ __launch_bounds__(256) void red_m(const u16* P, const float* W2, const float* b2, float* wv){
  int w = threadIdx.x >> 6, l = threadIdx.x & 63;
  size_t r = (size_t)blockIdx.x * 4 + w;
  int n0 = l * 8;
  uint4 u = *(const uint4*)(P + r * 512 + n0);
  u32 ua[4] = {u.x, u.y, u.z, u.w};
  float acc = 0.f;
#pragma unroll
  for (int j = 0; j < 8; ++j){
    float pv = bf2f((u16)(ua[j >> 1] >> ((j & 1) * 16)));
    acc += gelu_exact(pv) * W2[n0 + j];
  }
  for (int d = 1; d < 64; d <<= 1) acc += __shfl_xor(acc, d);
  if (l == 0) wv[r] = acc + b2[0];
}

__global__ __launch_bounds__(64) void fi_k(const float* wv, float* out){
  int b = blockIdx.x, l = threadIdx.x;
  float x[8]; float mx = -3.0e38f;
#pragma unroll
  for (int i = 0; i < 8; ++i){ x[i] = wv[b * 512 + i * 64 + l]; mx = fmaxf(mx, x[i]); }
  for (int d = 1; d < 64; d <<= 1) mx = fmaxf(mx, __shfl_xor(mx, d));
  float s = 0.f;
#pragma unroll
  for (int i = 0; i < 8; ++i){ x[i] = __expf(x[i] - mx); s += x[i]; }
  for (int d = 1; d < 64; d <<= 1) s += __shfl_xor(s, d);
  float inv = 1.0f / s;
#pragma unroll
  for (int i = 0; i < 8; ++i) out[b * 512 + i * 64 + l] = x[i] * inv;
}

// ---------------------------------------------------------------------------
extern "C" void kernel_launch(void* const* d_in, const int* in_sizes, int n_in,
                              void* d_out, int out_size, void* d_ws, size_t ws_size,
                              hipStream_t stream){
  const float* x    = (const float*)d_in[0];
  const float* Wq   = (const float*)d_in[1];
  const float* bq   = (const float*)d_in[2];
  const float* Wk   = (const float*)d_in[3];
  const float* bk   = (const float*)d_in[4];
  const float* Wv   = (const float*)d_in[5];
  const float* bv   = (const float*)d_in[6];
  const float* gq   = (const float*)d_in[7];
  const float* Bq   = (const float*)d_in[8];
  const float* gk   = (const float*)d_in[9];
  const float* Bk   = (const float*)d_in[10];
  const float* gv   = (const float*)d_in[11];
  const float* Bv   = (const float*)d_in[12];
  const float* Wo   = (const float*)d_in[13];
  const float* bo   = (const float*)d_in[14];
  const float* g_ln = (const float*)d_in[15];
  const float* b_ln = (const float*)d_in[16];
  const float* W1   = (const float*)d_in[17];
  const float* b1   = (const float*)d_in[18];
  const float* W2   = (const float*)d_in[19];
  const float* b2   = (const float*)d_in[20];
  float* out = (float*)d_out;

  char* ws = (char*)d_ws;
  u16*   WT    = (u16*)(ws);                         // 2,621,440 B
  float* biasS = (float*)(ws + 2621440);             // 6144
  float* gS    = (float*)(ws + 2627584);             // 6144
  float* BS    = (float*)(ws + 2633728);             // 6144
  u16*   xb    = (u16*)(ws + 2639872);               // 16,777,216 (reused as `at` after qkv gemm)
  u16*   at    = xb;
  u16*   P     = (u16*)(ws + 19417088);              // 50,331,648 ([16384][1536])
  u16*   Po    = P;                                  // [16384][512], P dead after attn
  u16*   x2b   = (u16*)((char*)P + 16777216);
  u16*   P1    = (u16*)((char*)P + 33554432);
  float* wvec  = (float*)(ws + 69748736);            // 65,536

  prep_all<<<9222, 256, 0, stream>>>(x, Wq, Wk, Wv, Wo, W1, bq, bk, bv,
                                     gq, Bq, gk, Bk, gv, Bv, WT, xb, biasS, gS, BS);

  gemm2<<<dim3(128, 12), 256, 0, stream>>>(xb, WT, biasS, P, 1536);       // fused QKV
  ln3<<<12288, 256, 0, stream>>>(P, gS, BS);                              // in-place, q pre-scaled

  attn_k<<<512, 512, 0, stream>>>(P, at);

  gemm2<<<dim3(128, 4), 256, 0, stream>>>(at, WT + 3 * 262144, bo, Po, 512);
  ln_o<<<4096, 256, 0, stream>>>(Po, x, g_ln, b_ln, out, x2b);

  gemm2<<<dim3(128, 4), 256, 0, stream>>>(x2b, WT + 4 * 262144, b1, P1, 512);
  red_m<<<4096, 256, 0, stream>>>(P1, W2, b2, wvec);
  fi_k<<<32, 64, 0, stream>>>(wvec, out + 8388608);
}